// Round 5
// baseline (9000.049 us; speedup 1.0000x reference)
//
#include <hip/hip_runtime.h>
#include <hip/hip_fp16.h>

// RNN_14078902797083: 2-layer tanh RNN + FC + softmax, fp32 in/out.
// B=64, T=2048, IN=256, H=512, NCLASS=2.
//
// R9 = R8 with the s_sleep constant-arg compile fix.
// R8: row-split scan across WG pairs. R7 hit two walls: 512 fp16 weights
// per thread (256 regs, allocator caps arch VGPRs at 128 -> AGPR copy tax)
// and 64/256 CUs. Now 128 WGs: WG (b, r) owns rows r*256..+255 of batch b
// -> 128 weight VGPRs/thread, 128 dot2/thread/step. Halves exchange 256
// fp16/step via self-validating tagged-u64 L2 atomics (R4-proven pattern,
// 1/64th the poll footprint: 128 lanes x 8 B, s_sleep backoff; mutual
// dependency bounds skew to 1 step; parity-double-buffered slots). Poll
// sits only on partner-k-half waves (2-wave LDS flag, not syncthreads);
// own-k-half waves crunch meanwhile. Pairs (b, b+64) co-XCD under bid%8.
// hxg buffers reuse the dead WT region (proven ws bounds); 84 KB LDS pad
// forces 1 WG/CU.

#define BB 64
#define TT 2048
#define IN 256
#define HH 512
#define MM (BB * TT)          // 131072 rows

// workspace layout (bytes) — within the R0-proven footprint
#define BUF0_OFF 0ull                      // [B][T][H] f32 = 256 MB (xw0 -> h1 -> xw1, in place)
#define WT_OFF   268435456ull              // W^T scratch, 1 MB (gemm phases only)
#define H2L_OFF  269484032ull              // [B][H] f32 last hidden = 128 KB
// hxg0/hxg1 live inside the WT MB (disjoint lifetimes vs gemm/transpose):
#define HXG0_OFF WT_OFF                    // [2][2][64][128] u64 = 256 KB
#define HXG1_OFF (WT_OFF + 262144ull)      // [2][2][64][128] u64 = 256 KB
#define HXG_WORDS 32768                    // 2*2*64*128

#define SCAN_SMEM 86016                    // 84 KB pad -> exactly 1 WG/CU

#define AGENT __HIP_MEMORY_SCOPE_AGENT

__device__ __forceinline__ unsigned long long ald64(const unsigned long long* p) {
    return __hip_atomic_load(p, __ATOMIC_RELAXED, AGENT);
}
__device__ __forceinline__ void ast64(unsigned long long* p, unsigned long long v) {
    __hip_atomic_store(p, v, __ATOMIC_RELAXED, AGENT);
}

typedef _Float16 v2h __attribute__((ext_vector_type(2)));

__device__ __forceinline__ float fdot2u(unsigned a, unsigned b, float c) {
#if __has_builtin(__builtin_amdgcn_fdot2)
    union { unsigned u; v2h h; } ua, ub;
    ua.u = a; ub.u = b;
    return __builtin_amdgcn_fdot2(ua.h, ub.h, c, false);
#else
    __half2 ah = *reinterpret_cast<__half2*>(&a);
    __half2 bh = *reinterpret_cast<__half2*>(&b);
    float2 fa = __half22float2(ah), fb = __half22float2(bh);
    return fmaf(fa.y, fb.y, fmaf(fa.x, fb.x, c));
#endif
}

__device__ __forceinline__ unsigned pk2(float x, float y) {
    unsigned lo = (unsigned)__half_as_ushort(__float2half(x));
    unsigned hi = (unsigned)__half_as_ushort(__float2half(y));
    return lo | (hi << 16);
}

__device__ __forceinline__ unsigned rdlane(unsigned v, int lane) {
    return (unsigned)__builtin_amdgcn_readlane((int)v, lane);
}

// fast tanh: copysign((1-e)/(1+e), x), e = exp(-2|x|). No overflow; ~2e-6 abs err.
__device__ __forceinline__ float fast_tanh(float x) {
    const float ax = __builtin_fabsf(x);
    const float e  = __expf(-2.f * ax);
    const float r  = (1.f - e) * __builtin_amdgcn_rcpf(1.f + e);
    return __builtin_copysignf(r, x);
}

// -------------------- zero init for tagged exchange words --------------------
__global__ void zero_u64(unsigned long long* a, int n)
{
    int i = blockIdx.x * blockDim.x + threadIdx.x;
    if (i < n) a[i] = 0ull;
}

// -------------------- W transpose: W[512][K] -> WT[K][512] --------------------
__global__ void transpose_w(const float* __restrict__ W, float* __restrict__ WT, int K)
{
    __shared__ float tile[32][33];
    const int k0 = blockIdx.x * 32;
    const int c0 = blockIdx.y * 32;
    const int tx = threadIdx.x & 31;
    const int ty = threadIdx.x >> 5;          // 0..7
    #pragma unroll
    for (int i = ty; i < 32; i += 8)
        tile[i][tx] = W[(size_t)(c0 + i) * K + k0 + tx];   // coalesced along k
    __syncthreads();
    #pragma unroll
    for (int i = ty; i < 32; i += 8)
        WT[(size_t)(k0 + i) * HH + c0 + tx] = tile[tx][i]; // coalesced along c
}

// -------------------- input projection GEMM: out = A @ W^T + (b1+b2) ----------
// A [M][K] (may alias out), WT [K][512], out [M][512]. 32 rows/WG, full N.
// Full-K A staging in LDS BEFORE any write -> in-place safe per 32-row block.
template <int K>
__global__ __launch_bounds__(256, 2)
void gemm_xw(const float* A, const float* __restrict__ WT,
             const float* __restrict__ b1, const float* __restrict__ b2,
             float* out)
{
    extern __shared__ char smem[];
    float* As = (float*)smem;                 // [32][K]
    const int m0 = blockIdx.x * 32;
    const int tid = threadIdx.x;

    const float* Ab = A + (size_t)m0 * K;
    #pragma unroll
    for (int i = 0; i < (32 * K) / 1024; ++i) {
        const int idx = tid * 4 + i * 1024;
        *(float4*)&As[idx] = *(const float4*)&Ab[idx];
    }
    __syncthreads();

    const int tc = tid & 63;                  // col base lane; cols c = tc + 64*cc
    const int r0 = (tid >> 6) * 8;            // 8 rows per thread

    float acc[8][8];
    #pragma unroll
    for (int cc = 0; cc < 8; ++cc) {
        const int c = tc + 64 * cc;
        const float bb = b1[c] + b2[c];
        #pragma unroll
        for (int rr = 0; rr < 8; ++rr) acc[rr][cc] = bb;
    }

    #pragma unroll 2
    for (int k = 0; k < K; k += 4) {
        float4 av4[8];
        #pragma unroll
        for (int rr = 0; rr < 8; ++rr)
            av4[rr] = *(const float4*)&As[(r0 + rr) * K + k];   // wave-uniform: broadcast
        #pragma unroll
        for (int kk = 0; kk < 4; ++kk) {
            float wv[8];
            #pragma unroll
            for (int cc = 0; cc < 8; ++cc)
                wv[cc] = WT[(size_t)(k + kk) * HH + tc + 64 * cc];  // lane-consecutive: coalesced
            #pragma unroll
            for (int rr = 0; rr < 8; ++rr) {
                const float a = ((const float*)&av4[rr])[kk];
                #pragma unroll
                for (int cc = 0; cc < 8; ++cc)
                    acc[rr][cc] = fmaf(a, wv[cc], acc[rr][cc]);
            }
        }
    }

    #pragma unroll
    for (int rr = 0; rr < 8; ++rr) {
        float* orow = out + (size_t)(m0 + r0 + rr) * HH;
        #pragma unroll
        for (int cc = 0; cc < 8; ++cc)
            orow[tc + 64 * cc] = acc[rr][cc];
    }
}

// -------------------- row-split recurrent scan: 2 WGs per batch ---------------
// WG (b, r): rows [r*256, r*256+256). Thread j: partial of row r*256+(j&255)
// over k in [ (j>>8)*256, +256 ). Halves exchange h via tagged u64 atomics.
template <bool WRITE_SEQ>
__global__ __launch_bounds__(512, 2)
void scan_split(const float* xw,                 // [B][T][H]
                const float* __restrict__ Whh,   // [H][H]
                float* hseq,                     // WRITE_SEQ: [B][T][H] (alias xw); else [B][H]
                unsigned long long* __restrict__ hxg)  // [2][2][64][128] tagged words
{
    extern __shared__ char smem[];
    float*    red   = (float*)smem;               // [512]  red[q*256+g]
    unsigned* hbuf  = (unsigned*)(smem + 2048);   // [2 slot][2 half][128] packed fp16 pairs
    int*      pflag = (int*)(smem + 4096);        // pull-completion counter

    const int wg = blockIdx.x;
    const int r  = wg >> 6;          // row-half 0/1  (pairs (b, b+64): same XCD under bid%8)
    const int b  = wg & 63;          // batch
    const int j  = threadIdx.x;
    const int q  = j >> 8;           // k-half this thread accumulates
    const int g  = j & 255;
    const int l  = j & 63;

    if (j == 0) *pflag = 0;

    // ---- one-time: weights rows r*256+g, k in [q*256, +256), 32 uint4 fp16 ----
    const float* wrow = Whh + (size_t)(r * 256 + g) * HH + q * 256;
    uint4 w4[32];
    #pragma unroll
    for (int c = 0; c < 32; ++c) {
        const float4 f0 = *(const float4*)(wrow + c * 8);
        const float4 f1 = *(const float4*)(wrow + c * 8 + 4);
        w4[c].x = pk2(f0.x, f0.y); w4[c].y = pk2(f0.z, f0.w);
        w4[c].z = pk2(f1.x, f1.y); w4[c].w = pk2(f1.z, f1.w);
    }
    __syncthreads();

    const float* xrow = xw + (size_t)b * TT * HH + (r * 256 + g);
    float xw_cur = 0.f, xw_n1 = 0.f;
    if (j < 256) { xw_cur = xrow[0]; xw_n1 = xrow[HH]; }
    float* srow = nullptr;
    if (WRITE_SEQ) srow = hseq + (size_t)b * TT * HH + (r * 256 + g);

    for (int t = 0; t < TT; ++t) {
        const int sl = t & 1;        // slot holding h_{t-1} (tag t)

        // ---- pull partner half (only partner-k-half waves; own waves skip) ----
        if (t > 0 && q != r) {
            if (g < 128) {
                const unsigned long long* src =
                    hxg + (((size_t)sl * 2 + (1 - r)) * 64 + b) * 128 + g;
                unsigned long long v = ald64(src);
                int rr = 0;
                while ((unsigned)(v >> 32) != (unsigned)t) {
                    if (rr < 2) __builtin_amdgcn_s_sleep(1);
                    else        __builtin_amdgcn_s_sleep(4);
                    ++rr;
                    v = ald64(src);
                }
                hbuf[(sl * 2 + q) * 128 + g] = (unsigned)v;
                if (l == 0)
                    __hip_atomic_fetch_add(pflag, 1, __ATOMIC_RELEASE,
                                           __HIP_MEMORY_SCOPE_WORKGROUP);
            }
            while (__hip_atomic_load(pflag, __ATOMIC_ACQUIRE,
                                     __HIP_MEMORY_SCOPE_WORKGROUP) < 2 * t) { }
        }

        // ---- partial dot: 128 dot2 over this thread's k-half ----
        float a0 = 0.f, a1 = 0.f, a2 = 0.f, a3 = 0.f;
        if (t > 0) {
            const unsigned* hp = &hbuf[(sl * 2 + q) * 128];
            const uint2 hv = *(const uint2*)(hp + 2 * l);   // lane-spread: uints 2l,2l+1
            #pragma unroll
            for (int c = 0; c < 16; ++c) {                  // chunks 0..15: LDS broadcast
                const uint4 hb = *(const uint4*)(hp + 4 * c);
                a0 = fdot2u(w4[c].x, hb.x, a0);
                a1 = fdot2u(w4[c].y, hb.y, a1);
                a2 = fdot2u(w4[c].z, hb.z, a2);
                a3 = fdot2u(w4[c].w, hb.w, a3);
            }
            #pragma unroll
            for (int c = 16; c < 32; ++c) {                 // chunks 16..31: readlane
                const unsigned s0 = rdlane(hv.x, 2 * c);
                const unsigned s1 = rdlane(hv.y, 2 * c);
                const unsigned s2 = rdlane(hv.x, 2 * c + 1);
                const unsigned s3 = rdlane(hv.y, 2 * c + 1);
                a0 = fdot2u(w4[c].x, s0, a0);
                a1 = fdot2u(w4[c].y, s1, a1);
                a2 = fdot2u(w4[c].z, s2, a2);
                a3 = fdot2u(w4[c].w, s3, a3);
            }
        }
        red[j] = (a0 + a1) + (a2 + a3);
        __syncthreads();

        // ---- combine + tanh + publish (threads 0..255, row = r*256+j) ----
        if (j < 256) {
            const float z = xw_cur + red[j] + red[256 + j];
            const float h = fast_tanh(z);
            const int s2 = (t + 1) & 1;
            ((unsigned short*)&hbuf[(s2 * 2 + r) * 128])[j] =
                __half_as_ushort(__float2half(h));
            const float hnext = __shfl_down(h, 1);
            if ((j & 1) == 0) {
                const unsigned long long word =
                    ((unsigned long long)(unsigned)(t + 1) << 32) |
                    (unsigned long long)pk2(h, hnext);
                ast64(hxg + (((size_t)s2 * 2 + r) * 64 + b) * 128 + (j >> 1), word);
            }
            if (WRITE_SEQ) {
                srow[(size_t)t * HH] = h;    // in-place over xw[b][t][row]: own element
            } else if (t == TT - 1) {
                hseq[b * HH + r * 256 + j] = h;
            }
            const int t2 = (t + 2 < TT) ? (t + 2) : (TT - 1);
            xw_cur = xw_n1;
            xw_n1  = xrow[(size_t)t2 * HH];
        }
        __syncthreads();
    }
}

// -------------------- FC + softmax --------------------
__global__ void fc_kernel(const float* __restrict__ h2, const float* __restrict__ w,
                          const float* __restrict__ bvec, float* __restrict__ out)
{
    const int b = threadIdx.x;   // 64 threads
    float z0 = bvec[0], z1 = bvec[1];
    #pragma unroll 4
    for (int k = 0; k < HH; k += 4) {
        float4 h  = *(const float4*)&h2[b * HH + k];
        float4 w0 = *(const float4*)&w[k];
        float4 w1 = *(const float4*)&w[HH + k];
        z0 += h.x * w0.x + h.y * w0.y + h.z * w0.z + h.w * w0.w;
        z1 += h.x * w1.x + h.y * w1.y + h.z * w1.z + h.w * w1.w;
    }
    const float m  = fmaxf(z0, z1);
    const float e0 = expf(z0 - m), e1 = expf(z1 - m);
    const float inv = 1.f / (e0 + e1);
    out[b * 2 + 0] = e0 * inv;
    out[b * 2 + 1] = e1 * inv;
}

extern "C" void kernel_launch(void* const* d_in, const int* in_sizes, int n_in,
                              void* d_out, int out_size, void* d_ws, size_t ws_size,
                              hipStream_t stream)
{
    (void)in_sizes; (void)n_in; (void)out_size; (void)ws_size;
    const float* x    = (const float*)d_in[0];
    const float* Wih0 = (const float*)d_in[1];
    const float* Whh0 = (const float*)d_in[2];
    const float* bih0 = (const float*)d_in[3];
    const float* bhh0 = (const float*)d_in[4];
    const float* Wih1 = (const float*)d_in[5];
    const float* Whh1 = (const float*)d_in[6];
    const float* bih1 = (const float*)d_in[7];
    const float* bhh1 = (const float*)d_in[8];
    const float* fcw  = (const float*)d_in[9];
    const float* fcb  = (const float*)d_in[10];
    float* out = (float*)d_out;

    char* ws = (char*)d_ws;
    float* buf0 = (float*)(ws + BUF0_OFF);
    float* WT   = (float*)(ws + WT_OFF);
    float* h2l  = (float*)(ws + H2L_OFF);
    unsigned long long* hxg0 = (unsigned long long*)(ws + HXG0_OFF);
    unsigned long long* hxg1 = (unsigned long long*)(ws + HXG1_OFF);

    static bool attr_done = false;
    if (!attr_done) {
        (void)hipFuncSetAttribute((const void*)scan_split<true>,
                                  hipFuncAttributeMaxDynamicSharedMemorySize, SCAN_SMEM);
        (void)hipFuncSetAttribute((const void*)scan_split<false>,
                                  hipFuncAttributeMaxDynamicSharedMemorySize, SCAN_SMEM);
        attr_done = true;
    }

    // ---- layer 0 ----
    transpose_w<<<dim3(IN / 32, HH / 32), dim3(256), 0, stream>>>(Wih0, WT, IN);
    gemm_xw<IN><<<dim3(MM / 32), dim3(256), 32 * IN * 4, stream>>>(x, WT, bih0, bhh0, buf0);
    // WT consumed; its region now becomes hxg0
    zero_u64<<<dim3(HXG_WORDS / 256), dim3(256), 0, stream>>>(hxg0, HXG_WORDS);
    scan_split<true><<<dim3(2 * BB), dim3(512), SCAN_SMEM, stream>>>(buf0, Whh0, buf0, hxg0);

    // ---- layer 1 (transpose clobbers hxg0 region: scan0 already done) ----
    transpose_w<<<dim3(HH / 32, HH / 32), dim3(256), 0, stream>>>(Wih1, WT, HH);
    gemm_xw<HH><<<dim3(MM / 32), dim3(256), 32 * HH * 4, stream>>>(buf0, WT, bih1, bhh1, buf0);
    zero_u64<<<dim3(HXG_WORDS / 256), dim3(256), 0, stream>>>(hxg1, HXG_WORDS);
    scan_split<false><<<dim3(2 * BB), dim3(512), SCAN_SMEM, stream>>>(buf0, Whh1, h2l, hxg1);

    // ---- FC + softmax ----
    fc_kernel<<<dim3(1), dim3(64), 0, stream>>>(h2l, fcw, fcb, out);
}